// Round 10
// baseline (1730.945 us; speedup 1.0000x reference)
//
#include <hip/hip_runtime.h>
#include <math.h>

#define NN 100000
#define NE 400000
#define FI 64
#define HH 256
#define KT 50000

typedef unsigned short u16;
typedef __attribute__((ext_vector_type(8))) short bf16x8;
typedef __attribute__((ext_vector_type(4))) float f32x4;

__device__ __forceinline__ float leaky02(float x){ return x >= 0.f ? x : 0.2f*x; }
__device__ __forceinline__ float preluf(float x, float a){ return x >= 0.f ? x : a*x; }

__device__ __forceinline__ float wredmax(float v){
  #pragma unroll
  for (int o=32;o>0;o>>=1) v = fmaxf(v, __shfl_xor(v, o, 64));
  return v;
}
__device__ __forceinline__ float wredsum(float v){
  #pragma unroll
  for (int o=32;o>0;o>>=1) v += __shfl_xor(v, o, 64);
  return v;
}
// reduce across the 16 lanes of an l15 group
__device__ __forceinline__ float qredsum(float v){
  #pragma unroll
  for (int o=8;o>0;o>>=1) v += __shfl_xor(v, o, 64);
  return v;
}

__device__ __forceinline__ void atomicMaxF(float* a, float v){
  if (v >= 0.f) atomicMax((int*)a, __float_as_int(v));
  else atomicMin((unsigned int*)a, __float_as_uint(v));
}

__device__ __forceinline__ float4 bnprelu4(float4 v, float4 sc, float4 sh, float a){
  float4 r;
  r.x = preluf(v.x*sc.x+sh.x, a);
  r.y = preluf(v.y*sc.y+sh.y, a);
  r.z = preluf(v.z*sc.z+sh.z, a);
  r.w = preluf(v.w*sc.w+sh.w, a);
  return r;
}

__device__ __forceinline__ u16 f2bf(float f){
  unsigned u = __float_as_uint(f);
  unsigned r = u + 0x7FFFu + ((u>>16)&1u);
  return (u16)(r>>16);
}
__device__ __forceinline__ float bf2f(u16 h){
  return __uint_as_float(((unsigned)h)<<16);
}
// split 8 floats (two float4, k-order) into hi/lo bf16x8
__device__ __forceinline__ void split8(float4 a, float4 b, bf16x8& h, bf16x8& l){
  float va[8] = {a.x,a.y,a.z,a.w,b.x,b.y,b.z,b.w};
  #pragma unroll
  for (int j=0;j<8;j++){
    u16 hh = f2bf(va[j]);
    h[j] = (short)hh;
    l[j] = (short)f2bf(va[j] - bf2f(hh));
  }
}

// async global->LDS DMA, 16B per lane, dest = wave-uniform base + lane*16
__device__ __forceinline__ void gld_lds16(const u16* gsrc, u16* ldsdst){
  __builtin_amdgcn_global_load_lds((const __attribute__((address_space(1))) void*)gsrc,
                                   (__attribute__((address_space(3))) void*)ldsdst, 16, 0, 0);
}

// ---------------- CSR build ----------------
__global__ void k_count(const int* __restrict__ dst, int* __restrict__ deg){
  int e = blockIdx.x*blockDim.x + threadIdx.x;
  if (e < NE) atomicAdd(&deg[dst[e]], 1);
}

__global__ __launch_bounds__(1024) void k_scan1(const int* __restrict__ deg, int* __restrict__ rowptr, int* __restrict__ bsums){
  __shared__ int sm[1024];
  int t = threadIdx.x; int g = blockIdx.x*1024 + t;
  int v = (g < NN) ? deg[g] : 0;
  sm[t] = v; __syncthreads();
  for (int o=1;o<1024;o<<=1){
    int add = (t>=o)? sm[t-o] : 0;
    __syncthreads();
    sm[t] += add;
    __syncthreads();
  }
  if (g < NN) rowptr[g] = sm[t] - v;
  if (t == 1023) bsums[blockIdx.x] = sm[1023];
}

__global__ __launch_bounds__(128) void k_scan2(int* __restrict__ bsums, int nblk){
  __shared__ int sm[128];
  int t = threadIdx.x;
  int v = (t < nblk) ? bsums[t] : 0;
  sm[t] = v; __syncthreads();
  for (int o=1;o<128;o<<=1){
    int add = (t>=o)? sm[t-o] : 0;
    __syncthreads();
    sm[t] += add;
    __syncthreads();
  }
  if (t < nblk) bsums[t] = sm[t] - v;
}

__global__ __launch_bounds__(1024) void k_scan3(int* __restrict__ rowptr, const int* __restrict__ bsums, int* __restrict__ cursor){
  int g = blockIdx.x*1024 + threadIdx.x;
  if (g < NN){ int r = rowptr[g] + bsums[blockIdx.x]; rowptr[g] = r; cursor[g] = r; }
  if (blockIdx.x==0 && threadIdx.x==0) rowptr[NN] = NE;
}

__global__ void k_scatter(const int* __restrict__ src, const int* __restrict__ dst, int* __restrict__ cursor, int* __restrict__ adj){
  int e = blockIdx.x*blockDim.x + threadIdx.x;
  if (e < NE){ int d = dst[e]; int slot = atomicAdd(&cursor[d], 1); adj[slot] = src[e]; }
}

// ---------------- W pre-split: WtT[chunk][quad][plane][n][8] ----------------
__global__ __launch_bounds__(256) void k_splitW(const float* __restrict__ Wr, const float* __restrict__ Wl,
    u16* __restrict__ WtT){
  int idx = blockIdx.x*256 + threadIdx.x;    // 512*256
  int k = idx >> 8, n = idx & 255;
  float v = (k < HH) ? Wr[(size_t)k*HH + n] : Wl[(size_t)(k-HH)*HH + n];
  u16 hi = f2bf(v);
  float lo = v - bf2f(hi);
  size_t base = ((size_t)(k>>5))*16384 + (size_t)((k>>3)&3)*4096 + (size_t)n*8 + (k&7);
  WtT[base] = hi;
  WtT[base + 2048] = f2bf(lo);
}
__global__ __launch_bounds__(256) void k_splitW1(const float* __restrict__ W, u16* __restrict__ WtT){
  int idx = blockIdx.x*256 + threadIdx.x;    // 64*256
  int k = idx >> 8, n = idx & 255;
  float v = W[(size_t)k*HH + n];
  u16 hi = f2bf(v);
  float lo = v - bf2f(hi);
  size_t base = ((size_t)(k>>5))*16384 + (size_t)((k>>3)&3)*4096 + (size_t)n*8 + (k&7);
  WtT[base] = hi;
  WtT[base + 2048] = f2bf(lo);
}

// A-tile LDS layout: As[buf][group 0..7][m 0..63][8 u16], group stride 528 u16 (16B pad)
#define ASTRIDE 528
// B-tile LDS: Bs[buf][subblock 0..7][4096 u16 + 8 pad]; subblock = quad*2+plane
#define BSTRIDE 4104

// ---------------- GEMM1 (MFMA): h = x(N,64) @ W; fused asrc/adst row dots (r9 version) ----------------
__global__ __launch_bounds__(256, 2) void k_gemm1(const float* __restrict__ x,
    const u16* __restrict__ WtT,
    const float* __restrict__ a_src, const float* __restrict__ a_dst,
    float* __restrict__ out, float* __restrict__ asrc, float* __restrict__ adst){
  __shared__ u16 As[2][8*ASTRIDE];
  int tid = threadIdx.x;
  int row0 = blockIdx.x*64;
  int wave = tid>>6, lane = tid&63;
  int l15 = lane&15, quad = lane>>4;
  int col0 = wave*64;
  int sm_ = tid >> 2, sg = tid & 3;
  int sgrow = row0 + sm_; if (sgrow >= NN) sgrow = NN-1;
  f32x4 acc[4][4];
  #pragma unroll
  for (int mt=0;mt<4;mt++)
    #pragma unroll
    for (int nt=0;nt<4;nt++){ f32x4 z = {0.f,0.f,0.f,0.f}; acc[mt][nt] = z; }

  const u16* bbase = WtT + ((size_t)quad<<12) + (size_t)(col0 + l15)*8;
  bf16x8 B0h[4],B0l[4],B1h[4],B1l[4];
  float4 va0, va1;

  auto loadA = [&](int kc){
    va0 = *((const float4*)(x + (size_t)sgrow*FI + kc + sg*8));
    va1 = *((const float4*)(x + (size_t)sgrow*FI + kc + sg*8 + 4));
  };
  auto writeA = [&](int wb){
    bf16x8 h, l;
    split8(va0, va1, h, l);
    *((bf16x8*)&As[wb][sg*ASTRIDE + sm_*8]) = h;
    *((bf16x8*)&As[wb][(4+sg)*ASTRIDE + sm_*8]) = l;
  };
  auto loadB = [&](int ck, bf16x8 (&Bh)[4], bf16x8 (&Bl)[4]){
    const u16* bb = bbase + ((size_t)ck<<14);
    #pragma unroll
    for (int nt=0;nt<4;nt++){
      Bh[nt] = *((const bf16x8*)(bb + nt*128));
      Bl[nt] = *((const bf16x8*)(bb + 2048 + nt*128));
    }
  };
  auto mmacc = [&](int rb, bf16x8 (&Bh)[4], bf16x8 (&Bl)[4]){
    bf16x8 ah[4], al[4];
    #pragma unroll
    for (int mt=0;mt<4;mt++){
      int m = mt*16 + l15;
      ah[mt] = *((bf16x8*)&As[rb][quad*ASTRIDE + m*8]);
      al[mt] = *((bf16x8*)&As[rb][(4+quad)*ASTRIDE + m*8]);
    }
    #pragma unroll
    for (int nt=0;nt<4;nt++)
      #pragma unroll
      for (int mt=0;mt<4;mt++){
        acc[mt][nt] = __builtin_amdgcn_mfma_f32_16x16x32_bf16(ah[mt], Bh[nt], acc[mt][nt], 0, 0, 0);
        acc[mt][nt] = __builtin_amdgcn_mfma_f32_16x16x32_bf16(al[mt], Bh[nt], acc[mt][nt], 0, 0, 0);
        acc[mt][nt] = __builtin_amdgcn_mfma_f32_16x16x32_bf16(ah[mt], Bl[nt], acc[mt][nt], 0, 0, 0);
      }
  };

  loadA(0);
  writeA(0);          // buf 0
  loadA(32);
  loadB(0, B0h, B0l);
  // chunk 0
  __syncthreads();
  writeA(1);          // A(1) -> buf 1
  loadB(1, B1h, B1l);
  mmacc(0, B0h, B0l);
  // chunk 1
  __syncthreads();
  mmacc(1, B1h, B1l);

  // epilogue: store h + fused row-dots vs a_src/a_dst
  float ps[4][4], pd[4][4];
  #pragma unroll
  for (int mt=0;mt<4;mt++)
    #pragma unroll
    for (int r=0;r<4;r++){ ps[mt][r]=0.f; pd[mt][r]=0.f; }
  #pragma unroll
  for (int nt=0;nt<4;nt++){
    int c = col0 + nt*16 + l15;
    float av = a_src[c], dv = a_dst[c];
    #pragma unroll
    for (int mt=0;mt<4;mt++){
      int gbase = row0 + mt*16 + quad*4;
      #pragma unroll
      for (int r=0;r<4;r++){
        int grow = gbase + r;
        float v = acc[mt][nt][r];
        if (grow < NN) out[(size_t)grow*HH + c] = v;
        ps[mt][r] += v*av; pd[mt][r] += v*dv;
      }
    }
  }
  __syncthreads();
  float* sda = (float*)As;           // [4 waves][64 rows] asrc, then adst at +256
  float* sdd = sda + 256;
  #pragma unroll
  for (int mt=0;mt<4;mt++)
    #pragma unroll
    for (int r=0;r<4;r++){
      float s = qredsum(ps[mt][r]);
      float d = qredsum(pd[mt][r]);
      if (l15 == 0){
        int row = mt*16 + quad*4 + r;
        sda[wave*64 + row] = s;
        sdd[wave*64 + row] = d;
      }
    }
  __syncthreads();
  if (tid < 64){
    int grow = row0 + tid;
    if (grow < NN){
      asrc[grow] = sda[tid] + sda[64+tid] + sda[128+tid] + sda[192+tid];
      adst[grow] = sdd[tid] + sdd[64+tid] + sdd[128+tid] + sdd[192+tid];
    }
  }
}

// ---------------- GAT ----------------
__global__ __launch_bounds__(256) void k_gat(const float* __restrict__ h, const float* __restrict__ asrc,
     const float* __restrict__ adst, const int* __restrict__ rowptr, const int* __restrict__ adj,
     const float* __restrict__ bias, float* __restrict__ out){
  int node = blockIdx.x*4 + (threadIdx.x>>6);
  int lane = threadIdx.x & 63;
  int rs = rowptr[node], re = rowptr[node+1];
  float adsti = adst[node];
  float eself = leaky02(asrc[node] + adsti);
  float m = eself;
  for (int j = rs + lane; j < re; j += 64) m = fmaxf(m, leaky02(asrc[adj[j]] + adsti));
  m = wredmax(m);
  float ssum = 0.f;
  for (int j = rs + lane; j < re; j += 64) ssum += expf(leaky02(asrc[adj[j]] + adsti) - m);
  ssum = wredsum(ssum) + expf(eself - m);
  float denom = ssum + 1e-16f;
  int c0 = lane*4;
  float aself = expf(eself - m)/denom;
  float4 hv = *((const float4*)&h[(size_t)node*HH + c0]);
  float4 acc = make_float4(hv.x*aself, hv.y*aself, hv.z*aself, hv.w*aself);
  for (int jb = rs; jb < re; jb += 64){
    int cnt = min(64, re - jb);
    int sv = 0; float av = 0.f;
    if (lane < cnt){ sv = adj[jb+lane]; av = expf(leaky02(asrc[sv] + adsti) - m)/denom; }
    for (int jj=0; jj<cnt; jj++){
      int sb = __shfl(sv, jj, 64);
      float ab = __shfl(av, jj, 64);
      float4 q = *((const float4*)&h[(size_t)sb*HH + c0]);
      acc.x = fmaxf(acc.x, q.x*ab); acc.y = fmaxf(acc.y, q.y*ab);
      acc.z = fmaxf(acc.z, q.z*ab); acc.w = fmaxf(acc.w, q.w*ab);
    }
  }
  float4 bv = *((const float4*)&bias[c0]);
  acc.x += bv.x; acc.y += bv.y; acc.z += bv.z; acc.w += bv.w;
  *((float4*)&out[(size_t)node*HH + c0]) = acc;
}

// ---------------- BatchNorm ----------------
__global__ __launch_bounds__(256) void k_bnstats(const float* __restrict__ x, float* __restrict__ sums, float* __restrict__ sumsq){
  int c = threadIdx.x;
  float s = 0.f, q = 0.f;
  for (int r = blockIdx.x; r < NN; r += gridDim.x){
    float v = x[(size_t)r*HH + c];
    s += v; q += v*v;
  }
  atomicAdd(&sums[c], s);
  atomicAdd(&sumsq[c], q);
}

__global__ __launch_bounds__(256) void k_bnfin(const float* __restrict__ sums, const float* __restrict__ sumsq,
    const float* __restrict__ g, const float* __restrict__ b, float* __restrict__ scale, float* __restrict__ shift){
  int c = threadIdx.x;
  float mean = sums[c]/(float)NN;
  float var = sumsq[c]/(float)NN - mean*mean;
  float rstd = rsqrtf(var + 1e-5f);
  float sc = g[c]*rstd;
  scale[c] = sc; shift[c] = b[c] - mean*sc;
}

// ---------------- SAGE max-aggregate (bn1+prelu applied on the fly) ----------------
__global__ __launch_bounds__(256) void k_sageagg(const float* __restrict__ xin, const float* __restrict__ scale,
    const float* __restrict__ shift, const float* __restrict__ prelu, const int* __restrict__ rowptr,
    const int* __restrict__ adj, float* __restrict__ agg){
  int node = blockIdx.x*4 + (threadIdx.x>>6);
  int lane = threadIdx.x & 63;
  int rs = rowptr[node], re = rowptr[node+1];
  int c0 = lane*4;
  float slope = prelu[0];
  float4 sc = *((const float4*)&scale[c0]);
  float4 sh = *((const float4*)&shift[c0]);
  float4 acc = make_float4(-INFINITY,-INFINITY,-INFINITY,-INFINITY);
  for (int jb = rs; jb < re; jb += 64){
    int cnt = min(64, re - jb);
    int sv = (lane < cnt) ? adj[jb+lane] : 0;
    for (int jj=0; jj<cnt; jj++){
      int sb = __shfl(sv, jj, 64);
      float4 q = *((const float4*)&xin[(size_t)sb*HH + c0]);
      q = bnprelu4(q, sc, sh, slope);
      acc.x = fmaxf(acc.x, q.x); acc.y = fmaxf(acc.y, q.y);
      acc.z = fmaxf(acc.z, q.z); acc.w = fmaxf(acc.w, q.w);
    }
  }
  if (re == rs) acc = make_float4(0.f,0.f,0.f,0.f);
  *((float4*)&agg[(size_t)node*HH + c0]) = acc;
}

// ---------------- GEMM2 (MFMA): out = prelu(bn1(graw)) @ Wr + agg @ Wl + bl ----------------
// block 64m x 256n, 4 waves (64m x 64n each); A reg->LDS dbuf; B via global_load_lds DMA dbuf
// (zero VGPR cost, issued post-barrier, drains at next barrier). Fused BN2 stats. In-place safe.
__global__ __launch_bounds__(256, 1) void k_gemm2(const float* __restrict__ graw, const float* __restrict__ agg,
    const u16* __restrict__ WtT,
    const float* __restrict__ scale1, const float* __restrict__ shift1, const float* __restrict__ prelu1,
    const float* __restrict__ bl, float* __restrict__ out,
    float* __restrict__ sums, float* __restrict__ sumsq){
  __shared__ u16 As[2][8*ASTRIDE];    // 16.9 KB
  __shared__ u16 Bs[2][8*BSTRIDE];    // 131.3 KB
  int tid = threadIdx.x;
  int row0 = blockIdx.x*64;
  int wave = tid>>6, lane = tid&63;
  int l15 = lane&15, quad = lane>>4;
  int col0 = wave*64;
  int sm_ = tid >> 2, sg = tid & 3;
  int sgrow = row0 + sm_; if (sgrow >= NN) sgrow = NN-1;
  float slope = prelu1[0];
  f32x4 acc[4][4];
  #pragma unroll
  for (int mt=0;mt<4;mt++)
    #pragma unroll
    for (int nt=0;nt<4;nt++){ f32x4 z = {0.f,0.f,0.f,0.f}; acc[mt][nt] = z; }

  float4 va0, va1;

  auto loadA = [&](int kc){
    const float* ab = (kc < HH) ? graw : agg;
    int ac = (kc < HH) ? kc : kc - HH;
    va0 = *((const float4*)(ab + (size_t)sgrow*HH + ac + sg*8));
    va1 = *((const float4*)(ab + (size_t)sgrow*HH + ac + sg*8 + 4));
  };
  auto writeA = [&](int kc, int wb){
    float4 v0 = va0, v1 = va1;
    if (kc < HH){
      int kcol = kc + sg*8;
      v0 = bnprelu4(v0, *((const float4*)(scale1+kcol)),   *((const float4*)(shift1+kcol)),   slope);
      v1 = bnprelu4(v1, *((const float4*)(scale1+kcol+4)), *((const float4*)(shift1+kcol+4)), slope);
    }
    bf16x8 h, l;
    split8(v0, v1, h, l);
    *((bf16x8*)&As[wb][sg*ASTRIDE + sm_*8]) = h;
    *((bf16x8*)&As[wb][(4+sg)*ASTRIDE + sm_*8]) = l;
  };
  // DMA one 32KB B chunk into Bs[buf]: 32 x 1KB instrs, 8 per wave (wave handles its own quad)
  auto dmaB = [&](int ck, int buf){
    const u16* srcb = WtT + ((size_t)ck<<14) + (size_t)wave*4096;
    u16* dstb = &Bs[buf][wave*2*BSTRIDE];
    #pragma unroll
    for (int j=0;j<8;j++){
      int p = j>>2, part = j&3;
      gld_lds16(srcb + p*2048 + part*512 + lane*8, dstb + p*BSTRIDE + part*512);
    }
  };
  auto mmacc = [&](int rb){
    bf16x8 ah[4], al[4];
    #pragma unroll
    for (int mt=0;mt<4;mt++){
      int m = mt*16 + l15;
      ah[mt] = *((bf16x8*)&As[rb][quad*ASTRIDE + m*8]);
      al[mt] = *((bf16x8*)&As[rb][(4+quad)*ASTRIDE + m*8]);
    }
    #pragma unroll
    for (int nt=0;nt<4;nt++){
      int n = col0 + nt*16 + l15;
      bf16x8 bh = *((bf16x8*)&Bs[rb][(quad*2+0)*BSTRIDE + (size_t)n*8]);
      bf16x8 bo = *((bf16x8*)&Bs[rb][(quad*2+1)*BSTRIDE + (size_t)n*8]);
      #pragma unroll
      for (int mt=0;mt<4;mt++){
        acc[mt][nt] = __builtin_amdgcn_mfma_f32_16x16x32_bf16(ah[mt], bh, acc[mt][nt], 0, 0, 0);
        acc[mt][nt] = __builtin_amdgcn_mfma_f32_16x16x32_bf16(al[mt], bh, acc[mt][nt], 0, 0, 0);
        acc[mt][nt] = __builtin_amdgcn_mfma_f32_16x16x32_bf16(ah[mt], bo, acc[mt][nt], 0, 0, 0);
      }
    }
  };

  loadA(0);
  writeA(0, 0);
  loadA(32);
  dmaB(0, 0);
  #pragma unroll 1
  for (int k=0; k<16; k++){
    int rb = k & 1;
    __syncthreads();                      // A(k) visible; B(k) DMA drained; As[rb^1]/Bs[rb^1] free
    if (k < 15) writeA((k+1)*32, rb^1);   // va holds A(k+1)
    if (k < 14) loadA((k+2)*32);          // issued post-barrier; drains at next barrier
    if (k < 15) dmaB(k+1, rb^1);          // async DMA, zero VGPRs, drains at next barrier
    mmacc(rb);
  }

  // epilogue: bias, store, BN2 partial stats
  float psum[4], psq[4];
  #pragma unroll
  for (int nt=0;nt<4;nt++){
    int c = col0 + nt*16 + l15;
    float bcol = bl[c];
    float s=0.f, q=0.f;
    #pragma unroll
    for (int mt=0;mt<4;mt++){
      int gbase = row0 + mt*16 + quad*4;
      #pragma unroll
      for (int r=0;r<4;r++){
        int grow = gbase + r;
        float v = acc[mt][nt][r] + bcol;
        if (grow < NN){
          out[(size_t)grow*HH + c] = v;
          s += v; q += v*v;
        }
      }
    }
    psum[nt]=s; psq[nt]=q;
  }
  __syncthreads();
  float* sm2 = (float*)As;        // 512 floats
  sm2[tid] = 0.f; sm2[tid+256] = 0.f;
  __syncthreads();
  #pragma unroll
  for (int nt=0;nt<4;nt++){
    int c = col0 + nt*16 + l15;
    atomicAdd(&sm2[c], psum[nt]);
    atomicAdd(&sm2[256+c], psq[nt]);
  }
  __syncthreads();
  atomicAdd(&sums[tid], sm2[tid]);
  atomicAdd(&sumsq[tid], sm2[256+tid]);
}

// ---------------- pool GEMVs ----------------
__global__ __launch_bounds__(256) void k_gemv2(const float* __restrict__ x2raw, const float* __restrict__ scale2,
    const float* __restrict__ shift2, const float* __restrict__ prelu2,
    const float* __restrict__ Wrel, const float* __restrict__ Wroot, float* __restrict__ y2, float* __restrict__ y2r){
  int node = blockIdx.x*4 + (threadIdx.x>>6);
  int lane = threadIdx.x & 63;
  int c0 = lane*4;
  float slope = prelu2[0];
  float4 v = *((const float4*)&x2raw[(size_t)node*HH + c0]);
  float4 sc = *((const float4*)&scale2[c0]);
  float4 sh = *((const float4*)&shift2[c0]);
  v = bnprelu4(v, sc, sh, slope);
  float4 wr = *((const float4*)&Wrel[c0]);
  float4 wo = *((const float4*)&Wroot[c0]);
  float pr = v.x*wr.x + v.y*wr.y + v.z*wr.z + v.w*wr.w;
  float po = v.x*wo.x + v.y*wo.y + v.z*wo.z + v.w*wo.w;
  pr = wredsum(pr); po = wredsum(po);
  if (lane==0){ y2[node] = pr; y2r[node] = po; }
}

__global__ void k_score(const int* __restrict__ rowptr, const int* __restrict__ adj, const float* __restrict__ y2,
    const float* __restrict__ y2r, const float* __restrict__ brel, float* __restrict__ score, unsigned* __restrict__ keys){
  int i = blockIdx.x*blockDim.x + threadIdx.x;
  if (i >= NN) return;
  float s = 0.f;
  int rs = rowptr[i], re = rowptr[i+1];
  for (int j=rs;j<re;j++) s += y2[adj[j]];
  float sc = s + brel[0] + y2r[i];
  score[i] = sc;
  unsigned u = __float_as_uint(sc);
  u = (u & 0x80000000u) ? ~u : (u | 0x80000000u);
  keys[i] = u;
}

// ---------------- top-K radix select ----------------
__global__ void k_hist1(const unsigned* __restrict__ keys, unsigned* __restrict__ hist){
  int i = blockIdx.x*blockDim.x + threadIdx.x;
  if (i < NN) atomicAdd(&hist[keys[i]>>16], 1u);
}

__global__ __launch_bounds__(256) void k_findbin1(const unsigned* __restrict__ hist, unsigned* __restrict__ scal){
  __shared__ unsigned csum[256];
  __shared__ unsigned above[256];
  int t = threadIdx.x;
  int base = t*256;
  unsigned s = 0;
  for (int b=0;b<256;b++) s += hist[base+b];
  csum[t] = s; __syncthreads();
  if (t==0){ unsigned run=0; for (int u=255;u>=0;u--){ above[u]=run; run += csum[u]; } }
  __syncthreads();
  unsigned ab = above[t];
  if (ab < (unsigned)KT && ab + csum[t] >= (unsigned)KT){
    unsigned run = ab;
    for (int b = base+255; b >= base; b--){
      unsigned hb = hist[b];
      if (run + hb >= (unsigned)KT){ scal[0] = (unsigned)b; scal[1] = run; break; }
      run += hb;
    }
  }
}

__global__ void k_hist2(const unsigned* __restrict__ keys, const unsigned* __restrict__ scal, unsigned* __restrict__ hist){
  int i = blockIdx.x*blockDim.x + threadIdx.x;
  if (i < NN){ unsigned k = keys[i]; if ((k>>16) == scal[0]) atomicAdd(&hist[k & 0xFFFFu], 1u); }
}

__global__ __launch_bounds__(256) void k_findbin2(const unsigned* __restrict__ hist, unsigned* __restrict__ scal){
  __shared__ unsigned csum[256];
  __shared__ unsigned above[256];
  int t = threadIdx.x;
  unsigned target = (unsigned)KT - scal[1];
  int base = t*256;
  unsigned s = 0;
  for (int b=0;b<256;b++) s += hist[base+b];
  csum[t] = s; __syncthreads();
  if (t==0){ unsigned run=0; for (int u=255;u>=0;u--){ above[u]=run; run += csum[u]; } }
  __syncthreads();
  unsigned ab = above[t];
  if (ab < target && ab + csum[t] >= target){
    unsigned run = ab;
    for (int b = base+255; b >= base; b--){
      unsigned hb = hist[b];
      if (run + hb >= target){
        scal[2] = (scal[0] << 16) | (unsigned)b;
        scal[3] = target - run;
        scal[4] = hb;
        break;
      }
      run += hb;
    }
  }
}

__global__ void k_select(const unsigned* __restrict__ keys, const float* __restrict__ score,
    unsigned* __restrict__ scal, int* __restrict__ selidx, float* __restrict__ tvals){
  int i = blockIdx.x*blockDim.x + threadIdx.x;
  if (i >= NN) return;
  unsigned T = scal[2], needed = scal[3], cnteq = scal[4];
  unsigned k = keys[i];
  int s = 0;
  if (k > T) s = 1;
  else if (k == T){
    if (cnteq <= needed) s = 1;
    else {
      unsigned rank = 0;
      for (int j=0;j<i;j++) rank += (keys[j] == T) ? 1u : 0u;
      s = (rank < needed) ? 1 : 0;
    }
  }
  if (s){
    unsigned idx = atomicAdd(&scal[8], 1u);
    selidx[idx] = i;
    tvals[idx] = tanhf(score[i]);
  }
}

__global__ __launch_bounds__(256) void k_embed(const float* __restrict__ x2raw, const float* __restrict__ scale2,
    const float* __restrict__ shift2, const float* __restrict__ prelu2, const int* __restrict__ selidx,
    const float* __restrict__ tvals, float* __restrict__ embed){
  int c = threadIdx.x;
  float slope = prelu2[0];
  float scv = scale2[c], shv = shift2[c];
  float best = -INFINITY;
  for (int j = blockIdx.x; j < KT; j += gridDim.x){
    int r = selidx[j];
    float v = x2raw[(size_t)r*HH + c]*scv + shv;
    v = preluf(v, slope);
    best = fmaxf(best, v*tvals[j]);
  }
  atomicMaxF(&embed[c], best);
}

__global__ void k_initembed(float* __restrict__ embed){
  int i = threadIdx.x;
  if (i < 2*HH) embed[i] = -INFINITY;
}

// ---------------- head ----------------
__global__ __launch_bounds__(256) void k_head(const float* __restrict__ embed, const float* __restrict__ addf,
    const float* __restrict__ fc1W, const float* __restrict__ fc1b, const float* __restrict__ preluh,
    const float* __restrict__ fc2W, const float* __restrict__ fc2b, float* __restrict__ out){
  __shared__ float z[2*HH + 8];
  __shared__ float h1s[HH];
  __shared__ float red[4];
  int t = threadIdx.x;
  for (int i=t;i<2*HH;i+=256) z[i] = embed[i];
  if (t < 8) z[2*HH + t] = addf[t];
  __syncthreads();
  float acc = fc1b[t];
  for (int k=0;k<2*HH+8;k++) acc += z[k]*fc1W[(size_t)k*HH + t];
  float slope = preluh[0];
  h1s[t] = preluf(acc, slope);
  __syncthreads();
  float p = h1s[t]*fc2W[t];
  p = wredsum(p);
  if ((t & 63) == 0) red[t>>6] = p;
  __syncthreads();
  if (t == 0) out[0] = expf(red[0]+red[1]+red[2]+red[3] + fc2b[0]);
}

// ---------------- orchestration ----------------
extern "C" void kernel_launch(void* const* d_in, const int* in_sizes, int n_in,
                              void* d_out, int out_size, void* d_ws, size_t ws_size,
                              hipStream_t stream) {
  (void)in_sizes; (void)n_in; (void)out_size; (void)ws_size;
  char* ws = (char*)d_ws;
  size_t off = 0;
  auto alloc = [&](size_t bytes)->char*{
    char* p = ws + off;
    off = (off + bytes + 255) & ~(size_t)255;
    return p;
  };
  float* bufA   = (float*)alloc((size_t)NN*HH*4);   // h, later agg
  float* bufB   = (float*)alloc((size_t)NN*HH*4);   // gat out -> sage out (in-place) -> x2 source
  float* asrc   = (float*)alloc((size_t)NN*4);
  float* adst   = (float*)alloc((size_t)NN*4);
  int*   rowptr = (int*)  alloc((size_t)(NN+1)*4);
  int*   adj    = (int*)  alloc((size_t)NE*4);
  int*   cursor = (int*)  alloc((size_t)NN*4);
  int*   bsums  = (int*)  alloc(128*4);
  float* sums   = (float*)alloc((size_t)2*HH*4);
  float* sumsq  = sums + HH;
  float* scale1 = (float*)alloc((size_t)HH*4);
  float* shift1 = (float*)alloc((size_t)HH*4);
  float* scale2 = (float*)alloc((size_t)HH*4);
  float* shift2 = (float*)alloc((size_t)HH*4);
  float* y2     = (float*)alloc((size_t)NN*4);
  float* y2r    = (float*)alloc((size_t)NN*4);
  float* score  = (float*)alloc((size_t)NN*4);
  unsigned* keys= (unsigned*)alloc((size_t)NN*4);
  int*   selidx = (int*)  alloc((size_t)NN*4);
  float* tvals  = (float*)alloc((size_t)NN*4);
  unsigned* hist1 = (unsigned*)alloc(65536*4);
  unsigned* hist2 = (unsigned*)alloc(65536*4);
  unsigned* scal  = (unsigned*)alloc(64);
  float* embed  = (float*)alloc((size_t)2*HH*4);
  u16* WtT    = (u16*)alloc((size_t)16*16384*2);   // gemm2 weights, 512 KB
  u16* WtT1   = (u16*)alloc((size_t)2*16384*2);    // gemm1 weights, 64 KB

  const float* addf = (const float*)d_in[2];

  k_initembed<<<dim3(1), dim3(512), 0, stream>>>(embed);

  for (int br = 0; br < 2; br++){
    const float* x  = (const float*)d_in[br==0 ? 0 : 1];
    const int*   ei = (const int*)  d_in[br==0 ? 3 : 4];
    const int* esrc = ei;
    const int* edst = ei + NE;
    int p = br==0 ? 5 : 21;
    const float* gat_W    = (const float*)d_in[p+0];
    const float* gat_asrc = (const float*)d_in[p+1];
    const float* gat_adst = (const float*)d_in[p+2];
    const float* gat_b    = (const float*)d_in[p+3];
    const float* bn1_g    = (const float*)d_in[p+4];
    const float* bn1_b    = (const float*)d_in[p+5];
    const float* prelu1   = (const float*)d_in[p+6];
    const float* sage_Wl  = (const float*)d_in[p+7];
    const float* sage_bl  = (const float*)d_in[p+8];
    const float* sage_Wr  = (const float*)d_in[p+9];
    const float* bn2_g    = (const float*)d_in[p+10];
    const float* bn2_b    = (const float*)d_in[p+11];
    const float* prelu2   = (const float*)d_in[p+12];
    const float* pool_Wrel= (const float*)d_in[p+13];
    const float* pool_brel= (const float*)d_in[p+14];
    const float* pool_Wroot=(const float*)d_in[p+15];

    // CSR by dst
    hipMemsetAsync(cursor, 0, (size_t)NN*4, stream);
    k_count<<<dim3((NE+255)/256), dim3(256), 0, stream>>>(edst, cursor);
    k_scan1<<<dim3(98), dim3(1024), 0, stream>>>(cursor, rowptr, bsums);
    k_scan2<<<dim3(1), dim3(128), 0, stream>>>(bsums, 98);
    k_scan3<<<dim3(98), dim3(1024), 0, stream>>>(rowptr, bsums, cursor);
    k_scatter<<<dim3((NE+255)/256), dim3(256), 0, stream>>>(esrc, edst, cursor, adj);

    // W pre-splits (chunk-major fragment layout)
    k_splitW<<<dim3(512), dim3(256), 0, stream>>>(sage_Wr, sage_Wl, WtT);
    k_splitW1<<<dim3(64), dim3(256), 0, stream>>>(gat_W, WtT1);

    // GAT (MFMA gemm1 fuses the asrc/adst row-dots)
    k_gemm1<<<dim3((NN+63)/64), dim3(256), 0, stream>>>(x, WtT1, gat_asrc, gat_adst, bufA, asrc, adst);
    k_gat<<<dim3(25000), dim3(256), 0, stream>>>(bufA, asrc, adst, rowptr, adj, gat_b, bufB);

    // BN1
    hipMemsetAsync(sums, 0, (size_t)2*HH*4, stream);
    k_bnstats<<<dim3(512), dim3(256), 0, stream>>>(bufB, sums, sumsq);
    k_bnfin<<<dim3(1), dim3(256), 0, stream>>>(sums, sumsq, bn1_g, bn1_b, scale1, shift1);

    // SAGE (agg into bufA; MFMA GEMM in-place into bufB with fused BN2 stats)
    k_sageagg<<<dim3(25000), dim3(256), 0, stream>>>(bufB, scale1, shift1, prelu1, rowptr, adj, bufA);
    hipMemsetAsync(sums, 0, (size_t)2*HH*4, stream);
    k_gemm2<<<dim3((NN+63)/64), dim3(256), 0, stream>>>(bufB, bufA, WtT,
        scale1, shift1, prelu1, sage_bl, bufB, sums, sumsq);
    k_bnfin<<<dim3(1), dim3(256), 0, stream>>>(sums, sumsq, bn2_g, bn2_b, scale2, shift2);

    // SAGPool
    k_gemv2<<<dim3(25000), dim3(256), 0, stream>>>(bufB, scale2, shift2, prelu2, pool_Wrel, pool_Wroot, y2, y2r);
    k_score<<<dim3((NN+255)/256), dim3(256), 0, stream>>>(rowptr, adj, y2, y2r, pool_brel, score, keys);
    hipMemsetAsync(scal, 0, 64, stream);
    hipMemsetAsync(hist1, 0, 65536*4, stream);
    hipMemsetAsync(hist2, 0, 65536*4, stream);
    k_hist1<<<dim3((NN+255)/256), dim3(256), 0, stream>>>(keys, hist1);
    k_findbin1<<<dim3(1), dim3(256), 0, stream>>>(hist1, scal);
    k_hist2<<<dim3((NN+255)/256), dim3(256), 0, stream>>>(keys, scal, hist2);
    k_findbin2<<<dim3(1), dim3(256), 0, stream>>>(hist2, scal);
    k_select<<<dim3((NN+255)/256), dim3(256), 0, stream>>>(keys, score, scal, selidx, tvals);
    k_embed<<<dim3(256), dim3(256), 0, stream>>>(bufB, scale2, shift2, prelu2, selidx, tvals, embed + br*HH);
  }

  k_head<<<dim3(1), dim3(256), 0, stream>>>(embed, addf,
      (const float*)d_in[37], (const float*)d_in[38], (const float*)d_in[39],
      (const float*)d_in[40], (const float*)d_in[41], (float*)d_out);
}

// Round 11
// 1620.255 us; speedup vs baseline: 1.0683x; 1.0683x over previous
//
#include <hip/hip_runtime.h>
#include <math.h>

#define NN 100000
#define NE 400000
#define FI 64
#define HH 256
#define KT 50000

typedef unsigned short u16;
typedef __attribute__((ext_vector_type(8))) short bf16x8;
typedef __attribute__((ext_vector_type(4))) float f32x4;

__device__ __forceinline__ float leaky02(float x){ return x >= 0.f ? x : 0.2f*x; }
__device__ __forceinline__ float preluf(float x, float a){ return x >= 0.f ? x : a*x; }

__device__ __forceinline__ float wredmax(float v){
  #pragma unroll
  for (int o=32;o>0;o>>=1) v = fmaxf(v, __shfl_xor(v, o, 64));
  return v;
}
__device__ __forceinline__ float wredsum(float v){
  #pragma unroll
  for (int o=32;o>0;o>>=1) v += __shfl_xor(v, o, 64);
  return v;
}
// reduce across the 16 lanes of an l15 group
__device__ __forceinline__ float qredsum(float v){
  #pragma unroll
  for (int o=8;o>0;o>>=1) v += __shfl_xor(v, o, 64);
  return v;
}

__device__ __forceinline__ void atomicMaxF(float* a, float v){
  if (v >= 0.f) atomicMax((int*)a, __float_as_int(v));
  else atomicMin((unsigned int*)a, __float_as_uint(v));
}

__device__ __forceinline__ float4 bnprelu4(float4 v, float4 sc, float4 sh, float a){
  float4 r;
  r.x = preluf(v.x*sc.x+sh.x, a);
  r.y = preluf(v.y*sc.y+sh.y, a);
  r.z = preluf(v.z*sc.z+sh.z, a);
  r.w = preluf(v.w*sc.w+sh.w, a);
  return r;
}

__device__ __forceinline__ u16 f2bf(float f){
  unsigned u = __float_as_uint(f);
  unsigned r = u + 0x7FFFu + ((u>>16)&1u);
  return (u16)(r>>16);
}
__device__ __forceinline__ float bf2f(u16 h){
  return __uint_as_float(((unsigned)h)<<16);
}
// split 8 floats (two float4, k-order) into hi/lo bf16x8
__device__ __forceinline__ void split8(float4 a, float4 b, bf16x8& h, bf16x8& l){
  float va[8] = {a.x,a.y,a.z,a.w,b.x,b.y,b.z,b.w};
  #pragma unroll
  for (int j=0;j<8;j++){
    u16 hh = f2bf(va[j]);
    h[j] = (short)hh;
    l[j] = (short)f2bf(va[j] - bf2f(hh));
  }
}

// ---------------- CSR build ----------------
__global__ void k_count(const int* __restrict__ dst, int* __restrict__ deg){
  int e = blockIdx.x*blockDim.x + threadIdx.x;
  if (e < NE) atomicAdd(&deg[dst[e]], 1);
}

__global__ __launch_bounds__(1024) void k_scan1(const int* __restrict__ deg, int* __restrict__ rowptr, int* __restrict__ bsums){
  __shared__ int sm[1024];
  int t = threadIdx.x; int g = blockIdx.x*1024 + t;
  int v = (g < NN) ? deg[g] : 0;
  sm[t] = v; __syncthreads();
  for (int o=1;o<1024;o<<=1){
    int add = (t>=o)? sm[t-o] : 0;
    __syncthreads();
    sm[t] += add;
    __syncthreads();
  }
  if (g < NN) rowptr[g] = sm[t] - v;
  if (t == 1023) bsums[blockIdx.x] = sm[1023];
}

__global__ __launch_bounds__(128) void k_scan2(int* __restrict__ bsums, int nblk){
  __shared__ int sm[128];
  int t = threadIdx.x;
  int v = (t < nblk) ? bsums[t] : 0;
  sm[t] = v; __syncthreads();
  for (int o=1;o<128;o<<=1){
    int add = (t>=o)? sm[t-o] : 0;
    __syncthreads();
    sm[t] += add;
    __syncthreads();
  }
  if (t < nblk) bsums[t] = sm[t] - v;
}

__global__ __launch_bounds__(1024) void k_scan3(int* __restrict__ rowptr, const int* __restrict__ bsums, int* __restrict__ cursor){
  int g = blockIdx.x*1024 + threadIdx.x;
  if (g < NN){ int r = rowptr[g] + bsums[blockIdx.x]; rowptr[g] = r; cursor[g] = r; }
  if (blockIdx.x==0 && threadIdx.x==0) rowptr[NN] = NE;
}

__global__ void k_scatter(const int* __restrict__ src, const int* __restrict__ dst, int* __restrict__ cursor, int* __restrict__ adj){
  int e = blockIdx.x*blockDim.x + threadIdx.x;
  if (e < NE){ int d = dst[e]; int slot = atomicAdd(&cursor[d], 1); adj[slot] = src[e]; }
}

// ---------------- W pre-split: WtT[chunk][quad][plane][n][8] ----------------
__global__ __launch_bounds__(256) void k_splitW(const float* __restrict__ Wr, const float* __restrict__ Wl,
    u16* __restrict__ WtT){
  int idx = blockIdx.x*256 + threadIdx.x;    // 512*256
  int k = idx >> 8, n = idx & 255;
  float v = (k < HH) ? Wr[(size_t)k*HH + n] : Wl[(size_t)(k-HH)*HH + n];
  u16 hi = f2bf(v);
  float lo = v - bf2f(hi);
  size_t base = ((size_t)(k>>5))*16384 + (size_t)((k>>3)&3)*4096 + (size_t)n*8 + (k&7);
  WtT[base] = hi;
  WtT[base + 2048] = f2bf(lo);
}
__global__ __launch_bounds__(256) void k_splitW1(const float* __restrict__ W, u16* __restrict__ WtT){
  int idx = blockIdx.x*256 + threadIdx.x;    // 64*256
  int k = idx >> 8, n = idx & 255;
  float v = W[(size_t)k*HH + n];
  u16 hi = f2bf(v);
  float lo = v - bf2f(hi);
  size_t base = ((size_t)(k>>5))*16384 + (size_t)((k>>3)&3)*4096 + (size_t)n*8 + (k&7);
  WtT[base] = hi;
  WtT[base + 2048] = f2bf(lo);
}

// A-tile LDS layout: As[buf][group 0..7][m 0..63][8 u16], group stride 528 u16 (16B pad)
#define ASTRIDE 528

// ---------------- GEMM1 (MFMA): h = x(N,64) @ W; fused asrc/adst row dots ----------------
__global__ __launch_bounds__(256, 2) void k_gemm1(const float* __restrict__ x,
    const u16* __restrict__ WtT,
    const float* __restrict__ a_src, const float* __restrict__ a_dst,
    float* __restrict__ out, float* __restrict__ asrc, float* __restrict__ adst){
  __shared__ u16 As[2][8*ASTRIDE];
  int tid = threadIdx.x;
  int row0 = blockIdx.x*64;
  int wave = tid>>6, lane = tid&63;
  int l15 = lane&15, quad = lane>>4;
  int col0 = wave*64;
  int sm_ = tid >> 2, sg = tid & 3;
  int sgrow = row0 + sm_; if (sgrow >= NN) sgrow = NN-1;
  f32x4 acc[4][4];
  #pragma unroll
  for (int mt=0;mt<4;mt++)
    #pragma unroll
    for (int nt=0;nt<4;nt++){ f32x4 z = {0.f,0.f,0.f,0.f}; acc[mt][nt] = z; }

  const u16* bbase = WtT + ((size_t)quad<<12) + (size_t)(col0 + l15)*8;
  bf16x8 B0h[4],B0l[4],B1h[4],B1l[4];
  float4 va0, va1;

  auto loadA = [&](int kc){
    va0 = *((const float4*)(x + (size_t)sgrow*FI + kc + sg*8));
    va1 = *((const float4*)(x + (size_t)sgrow*FI + kc + sg*8 + 4));
  };
  auto writeA = [&](int wb){
    bf16x8 h, l;
    split8(va0, va1, h, l);
    *((bf16x8*)&As[wb][sg*ASTRIDE + sm_*8]) = h;
    *((bf16x8*)&As[wb][(4+sg)*ASTRIDE + sm_*8]) = l;
  };
  auto loadB = [&](int ck, bf16x8 (&Bh)[4], bf16x8 (&Bl)[4]){
    const u16* bb = bbase + ((size_t)ck<<14);
    #pragma unroll
    for (int nt=0;nt<4;nt++){
      Bh[nt] = *((const bf16x8*)(bb + nt*128));
      Bl[nt] = *((const bf16x8*)(bb + 2048 + nt*128));
    }
  };
  auto mmacc = [&](int rb, bf16x8 (&Bh)[4], bf16x8 (&Bl)[4]){
    bf16x8 ah[4], al[4];
    #pragma unroll
    for (int mt=0;mt<4;mt++){
      int m = mt*16 + l15;
      ah[mt] = *((bf16x8*)&As[rb][quad*ASTRIDE + m*8]);
      al[mt] = *((bf16x8*)&As[rb][(4+quad)*ASTRIDE + m*8]);
    }
    #pragma unroll
    for (int nt=0;nt<4;nt++)
      #pragma unroll
      for (int mt=0;mt<4;mt++){
        acc[mt][nt] = __builtin_amdgcn_mfma_f32_16x16x32_bf16(ah[mt], Bh[nt], acc[mt][nt], 0, 0, 0);
        acc[mt][nt] = __builtin_amdgcn_mfma_f32_16x16x32_bf16(al[mt], Bh[nt], acc[mt][nt], 0, 0, 0);
        acc[mt][nt] = __builtin_amdgcn_mfma_f32_16x16x32_bf16(ah[mt], Bl[nt], acc[mt][nt], 0, 0, 0);
      }
  };

  loadA(0);
  writeA(0);          // buf 0
  loadA(32);
  loadB(0, B0h, B0l);
  // chunk 0
  __syncthreads();
  writeA(1);          // A(1) -> buf 1
  loadB(1, B1h, B1l);
  mmacc(0, B0h, B0l);
  // chunk 1
  __syncthreads();
  mmacc(1, B1h, B1l);

  // epilogue: store h + fused row-dots vs a_src/a_dst
  float ps[4][4], pd[4][4];
  #pragma unroll
  for (int mt=0;mt<4;mt++)
    #pragma unroll
    for (int r=0;r<4;r++){ ps[mt][r]=0.f; pd[mt][r]=0.f; }
  #pragma unroll
  for (int nt=0;nt<4;nt++){
    int c = col0 + nt*16 + l15;
    float av = a_src[c], dv = a_dst[c];
    #pragma unroll
    for (int mt=0;mt<4;mt++){
      int gbase = row0 + mt*16 + quad*4;
      #pragma unroll
      for (int r=0;r<4;r++){
        int grow = gbase + r;
        float v = acc[mt][nt][r];
        if (grow < NN) out[(size_t)grow*HH + c] = v;
        ps[mt][r] += v*av; pd[mt][r] += v*dv;
      }
    }
  }
  __syncthreads();
  float* sda = (float*)As;           // [4 waves][64 rows] asrc, then adst at +256
  float* sdd = sda + 256;
  #pragma unroll
  for (int mt=0;mt<4;mt++)
    #pragma unroll
    for (int r=0;r<4;r++){
      float s = qredsum(ps[mt][r]);
      float d = qredsum(pd[mt][r]);
      if (l15 == 0){
        int row = mt*16 + quad*4 + r;
        sda[wave*64 + row] = s;
        sdd[wave*64 + row] = d;
      }
    }
  __syncthreads();
  if (tid < 64){
    int grow = row0 + tid;
    if (grow < NN){
      asrc[grow] = sda[tid] + sda[64+tid] + sda[128+tid] + sda[192+tid];
      adst[grow] = sdd[tid] + sdd[64+tid] + sdd[128+tid] + sdd[192+tid];
    }
  }
}

// ---------------- GAT: fast single-gather path for deg<=64 ----------------
__global__ __launch_bounds__(256) void k_gat(const float* __restrict__ h, const float* __restrict__ asrc,
     const float* __restrict__ adst, const int* __restrict__ rowptr, const int* __restrict__ adj,
     const float* __restrict__ bias, float* __restrict__ out){
  int node = blockIdx.x*4 + (threadIdx.x>>6);
  int lane = threadIdx.x & 63;
  int rs = rowptr[node], re = rowptr[node+1];
  int deg = re - rs;
  float adsti = adst[node];
  float eself = leaky02(asrc[node] + adsti);
  int c0 = lane*4;
  float4 acc;
  float4 bv = *((const float4*)&bias[c0]);
  if (deg <= 64){
    bool act = lane < deg;
    int sv = 0; float asv = 0.f;
    if (act){ sv = adj[rs + lane]; asv = asrc[sv]; }
    float e_l = act ? leaky02(asv + adsti) : -INFINITY;
    float m = fmaxf(eself, wredmax(e_l));
    float ex = act ? expf(e_l - m) : 0.f;
    float es = expf(eself - m);
    float denom = wredsum(ex) + es + 1e-16f;
    float aself = es/denom;
    float av = ex/denom;
    float4 hv = *((const float4*)&h[(size_t)node*HH + c0]);
    acc = make_float4(hv.x*aself, hv.y*aself, hv.z*aself, hv.w*aself);
    for (int jj=0; jj<deg; jj++){
      int sb = __shfl(sv, jj, 64);
      float ab = __shfl(av, jj, 64);
      float4 q = *((const float4*)&h[(size_t)sb*HH + c0]);
      acc.x = fmaxf(acc.x, q.x*ab); acc.y = fmaxf(acc.y, q.y*ab);
      acc.z = fmaxf(acc.z, q.z*ab); acc.w = fmaxf(acc.w, q.w*ab);
    }
  } else {
    float m = eself;
    for (int j = rs + lane; j < re; j += 64) m = fmaxf(m, leaky02(asrc[adj[j]] + adsti));
    m = wredmax(m);
    float ssum = 0.f;
    for (int j = rs + lane; j < re; j += 64) ssum += expf(leaky02(asrc[adj[j]] + adsti) - m);
    ssum = wredsum(ssum) + expf(eself - m);
    float denom = ssum + 1e-16f;
    float aself = expf(eself - m)/denom;
    float4 hv = *((const float4*)&h[(size_t)node*HH + c0]);
    acc = make_float4(hv.x*aself, hv.y*aself, hv.z*aself, hv.w*aself);
    for (int jb = rs; jb < re; jb += 64){
      int cnt = min(64, re - jb);
      int sv = 0; float av = 0.f;
      if (lane < cnt){ sv = adj[jb+lane]; av = expf(leaky02(asrc[sv] + adsti) - m)/denom; }
      for (int jj=0; jj<cnt; jj++){
        int sb = __shfl(sv, jj, 64);
        float ab = __shfl(av, jj, 64);
        float4 q = *((const float4*)&h[(size_t)sb*HH + c0]);
        acc.x = fmaxf(acc.x, q.x*ab); acc.y = fmaxf(acc.y, q.y*ab);
        acc.z = fmaxf(acc.z, q.z*ab); acc.w = fmaxf(acc.w, q.w*ab);
      }
    }
  }
  acc.x += bv.x; acc.y += bv.y; acc.z += bv.z; acc.w += bv.w;
  *((float4*)&out[(size_t)node*HH + c0]) = acc;
}

// ---------------- BatchNorm ----------------
__global__ __launch_bounds__(256) void k_bnstats(const float* __restrict__ x, float* __restrict__ sums, float* __restrict__ sumsq){
  int c = threadIdx.x;
  float s = 0.f, q = 0.f;
  for (int r = blockIdx.x; r < NN; r += gridDim.x){
    float v = x[(size_t)r*HH + c];
    s += v; q += v*v;
  }
  atomicAdd(&sums[c], s);
  atomicAdd(&sumsq[c], q);
}

__global__ __launch_bounds__(256) void k_bnfin(const float* __restrict__ sums, const float* __restrict__ sumsq,
    const float* __restrict__ g, const float* __restrict__ b, float* __restrict__ scale, float* __restrict__ shift){
  int c = threadIdx.x;
  float mean = sums[c]/(float)NN;
  float var = sumsq[c]/(float)NN - mean*mean;
  float rstd = rsqrtf(var + 1e-5f);
  float sc = g[c]*rstd;
  scale[c] = sc; shift[c] = b[c] - mean*sc;
}

// ---------------- SAGE max-aggregate (bn1+prelu applied on the fly) ----------------
__global__ __launch_bounds__(256) void k_sageagg(const float* __restrict__ xin, const float* __restrict__ scale,
    const float* __restrict__ shift, const float* __restrict__ prelu, const int* __restrict__ rowptr,
    const int* __restrict__ adj, float* __restrict__ agg){
  int node = blockIdx.x*4 + (threadIdx.x>>6);
  int lane = threadIdx.x & 63;
  int rs = rowptr[node], re = rowptr[node+1];
  int c0 = lane*4;
  float slope = prelu[0];
  float4 sc = *((const float4*)&scale[c0]);
  float4 sh = *((const float4*)&shift[c0]);
  float4 acc = make_float4(-INFINITY,-INFINITY,-INFINITY,-INFINITY);
  for (int jb = rs; jb < re; jb += 64){
    int cnt = min(64, re - jb);
    int sv = (lane < cnt) ? adj[jb+lane] : 0;
    for (int jj=0; jj<cnt; jj++){
      int sb = __shfl(sv, jj, 64);
      float4 q = *((const float4*)&xin[(size_t)sb*HH + c0]);
      q = bnprelu4(q, sc, sh, slope);
      acc.x = fmaxf(acc.x, q.x); acc.y = fmaxf(acc.y, q.y);
      acc.z = fmaxf(acc.z, q.z); acc.w = fmaxf(acc.w, q.w);
    }
  }
  if (re == rs) acc = make_float4(0.f,0.f,0.f,0.f);
  *((float4*)&agg[(size_t)node*HH + c0]) = acc;
}

// ---------------- GEMM2 (MFMA): out = prelu(bn1(graw)) @ Wr + agg @ Wl + bl ----------------
// r9 version: block 64m x 256n, 4 waves; dbuf A LDS, single barrier/chunk, B ping-pong regs.
__global__ __launch_bounds__(256, 2) void k_gemm2(const float* __restrict__ graw, const float* __restrict__ agg,
    const u16* __restrict__ WtT,
    const float* __restrict__ scale1, const float* __restrict__ shift1, const float* __restrict__ prelu1,
    const float* __restrict__ bl, float* __restrict__ out,
    float* __restrict__ sums, float* __restrict__ sumsq){
  __shared__ u16 As[2][8*ASTRIDE];
  int tid = threadIdx.x;
  int row0 = blockIdx.x*64;
  int wave = tid>>6, lane = tid&63;
  int l15 = lane&15, quad = lane>>4;
  int col0 = wave*64;
  int sm_ = tid >> 2, sg = tid & 3;
  int sgrow = row0 + sm_; if (sgrow >= NN) sgrow = NN-1;
  float slope = prelu1[0];
  f32x4 acc[4][4];
  #pragma unroll
  for (int mt=0;mt<4;mt++)
    #pragma unroll
    for (int nt=0;nt<4;nt++){ f32x4 z = {0.f,0.f,0.f,0.f}; acc[mt][nt] = z; }

  const u16* bbase = WtT + ((size_t)quad<<12) + (size_t)(col0 + l15)*8;
  bf16x8 B0h[4],B0l[4],B1h[4],B1l[4];
  float4 va0, va1;

  auto loadA = [&](int kc){
    const float* ab = (kc < HH) ? graw : agg;
    int ac = (kc < HH) ? kc : kc - HH;
    va0 = *((const float4*)(ab + (size_t)sgrow*HH + ac + sg*8));
    va1 = *((const float4*)(ab + (size_t)sgrow*HH + ac + sg*8 + 4));
  };
  auto writeA = [&](int kc, int wb){
    float4 v0 = va0, v1 = va1;
    if (kc < HH){
      int kcol = kc + sg*8;
      v0 = bnprelu4(v0, *((const float4*)(scale1+kcol)),   *((const float4*)(shift1+kcol)),   slope);
      v1 = bnprelu4(v1, *((const float4*)(scale1+kcol+4)), *((const float4*)(shift1+kcol+4)), slope);
    }
    bf16x8 h, l;
    split8(v0, v1, h, l);
    *((bf16x8*)&As[wb][sg*ASTRIDE + sm_*8]) = h;
    *((bf16x8*)&As[wb][(4+sg)*ASTRIDE + sm_*8]) = l;
  };
  auto loadB = [&](int ck, bf16x8 (&Bh)[4], bf16x8 (&Bl)[4]){
    const u16* bb = bbase + ((size_t)ck<<14);
    #pragma unroll
    for (int nt=0;nt<4;nt++){
      Bh[nt] = *((const bf16x8*)(bb + nt*128));
      Bl[nt] = *((const bf16x8*)(bb + 2048 + nt*128));
    }
  };
  auto body = [&](int k, int rb, bf16x8 (&Bh)[4], bf16x8 (&Bl)[4], bf16x8 (&nBh)[4], bf16x8 (&nBl)[4]){
    __syncthreads();
    if (k < 15) writeA((k+1)*32, rb^1);   // va holds A(k+1)
    if (k < 14) loadA((k+2)*32);          // issue post-barrier; drains at next barrier
    if (k < 15) loadB(k+1, nBh, nBl);
    bf16x8 ah[4], al[4];
    #pragma unroll
    for (int mt=0;mt<4;mt++){
      int m = mt*16 + l15;
      ah[mt] = *((bf16x8*)&As[rb][quad*ASTRIDE + m*8]);
      al[mt] = *((bf16x8*)&As[rb][(4+quad)*ASTRIDE + m*8]);
    }
    #pragma unroll
    for (int nt=0;nt<4;nt++)
      #pragma unroll
      for (int mt=0;mt<4;mt++){
        acc[mt][nt] = __builtin_amdgcn_mfma_f32_16x16x32_bf16(ah[mt], Bh[nt], acc[mt][nt], 0, 0, 0);
        acc[mt][nt] = __builtin_amdgcn_mfma_f32_16x16x32_bf16(al[mt], Bh[nt], acc[mt][nt], 0, 0, 0);
        acc[mt][nt] = __builtin_amdgcn_mfma_f32_16x16x32_bf16(ah[mt], Bl[nt], acc[mt][nt], 0, 0, 0);
      }
  };

  loadA(0);
  writeA(0, 0);
  loadA(32);
  loadB(0, B0h, B0l);
  #pragma unroll 1
  for (int k=0; k<16; k+=2){
    body(k,   0, B0h,B0l, B1h,B1l);
    body(k+1, 1, B1h,B1l, B0h,B0l);
  }

  // epilogue: bias, store, BN2 partial stats
  float psum[4], psq[4];
  #pragma unroll
  for (int nt=0;nt<4;nt++){
    int c = col0 + nt*16 + l15;
    float bcol = bl[c];
    float s=0.f, q=0.f;
    #pragma unroll
    for (int mt=0;mt<4;mt++){
      int gbase = row0 + mt*16 + quad*4;
      #pragma unroll
      for (int r=0;r<4;r++){
        int grow = gbase + r;
        float v = acc[mt][nt][r] + bcol;
        if (grow < NN){
          out[(size_t)grow*HH + c] = v;
          s += v; q += v*v;
        }
      }
    }
    psum[nt]=s; psq[nt]=q;
  }
  __syncthreads();
  float* sm2 = (float*)As;        // 512 floats
  sm2[tid] = 0.f; sm2[tid+256] = 0.f;
  __syncthreads();
  #pragma unroll
  for (int nt=0;nt<4;nt++){
    int c = col0 + nt*16 + l15;
    atomicAdd(&sm2[c], psum[nt]);
    atomicAdd(&sm2[256+c], psq[nt]);
  }
  __syncthreads();
  atomicAdd(&sums[tid], sm2[tid]);
  atomicAdd(&sumsq[tid], sm2[256+tid]);
}

// ---------------- pool GEMVs ----------------
__global__ __launch_bounds__(256) void k_gemv2(const float* __restrict__ x2raw, const float* __restrict__ scale2,
    const float* __restrict__ shift2, const float* __restrict__ prelu2,
    const float* __restrict__ Wrel, const float* __restrict__ Wroot, float* __restrict__ y2, float* __restrict__ y2r){
  int node = blockIdx.x*4 + (threadIdx.x>>6);
  int lane = threadIdx.x & 63;
  int c0 = lane*4;
  float slope = prelu2[0];
  float4 v = *((const float4*)&x2raw[(size_t)node*HH + c0]);
  float4 sc = *((const float4*)&scale2[c0]);
  float4 sh = *((const float4*)&shift2[c0]);
  v = bnprelu4(v, sc, sh, slope);
  float4 wr = *((const float4*)&Wrel[c0]);
  float4 wo = *((const float4*)&Wroot[c0]);
  float pr = v.x*wr.x + v.y*wr.y + v.z*wr.z + v.w*wr.w;
  float po = v.x*wo.x + v.y*wo.y + v.z*wo.z + v.w*wo.w;
  pr = wredsum(pr); po = wredsum(po);
  if (lane==0){ y2[node] = pr; y2r[node] = po; }
}

__global__ void k_score(const int* __restrict__ rowptr, const int* __restrict__ adj, const float* __restrict__ y2,
    const float* __restrict__ y2r, const float* __restrict__ brel, float* __restrict__ score, unsigned* __restrict__ keys){
  int i = blockIdx.x*blockDim.x + threadIdx.x;
  if (i >= NN) return;
  float s = 0.f;
  int rs = rowptr[i], re = rowptr[i+1];
  for (int j=rs;j<re;j++) s += y2[adj[j]];
  float sc = s + brel[0] + y2r[i];
  score[i] = sc;
  unsigned u = __float_as_uint(sc);
  u = (u & 0x80000000u) ? ~u : (u | 0x80000000u);
  keys[i] = u;
}

// ---------------- top-K radix select ----------------
__global__ void k_hist1(const unsigned* __restrict__ keys, unsigned* __restrict__ hist){
  int i = blockIdx.x*blockDim.x + threadIdx.x;
  if (i < NN) atomicAdd(&hist[keys[i]>>16], 1u);
}

__global__ __launch_bounds__(256) void k_findbin1(const unsigned* __restrict__ hist, unsigned* __restrict__ scal){
  __shared__ unsigned csum[256];
  __shared__ unsigned above[256];
  int t = threadIdx.x;
  int base = t*256;
  unsigned s = 0;
  for (int b=0;b<256;b++) s += hist[base+b];
  csum[t] = s; __syncthreads();
  if (t==0){ unsigned run=0; for (int u=255;u>=0;u--){ above[u]=run; run += csum[u]; } }
  __syncthreads();
  unsigned ab = above[t];
  if (ab < (unsigned)KT && ab + csum[t] >= (unsigned)KT){
    unsigned run = ab;
    for (int b = base+255; b >= base; b--){
      unsigned hb = hist[b];
      if (run + hb >= (unsigned)KT){ scal[0] = (unsigned)b; scal[1] = run; break; }
      run += hb;
    }
  }
}

__global__ void k_hist2(const unsigned* __restrict__ keys, const unsigned* __restrict__ scal, unsigned* __restrict__ hist){
  int i = blockIdx.x*blockDim.x + threadIdx.x;
  if (i < NN){ unsigned k = keys[i]; if ((k>>16) == scal[0]) atomicAdd(&hist[k & 0xFFFFu], 1u); }
}

__global__ __launch_bounds__(256) void k_findbin2(const unsigned* __restrict__ hist, unsigned* __restrict__ scal){
  __shared__ unsigned csum[256];
  __shared__ unsigned above[256];
  int t = threadIdx.x;
  unsigned target = (unsigned)KT - scal[1];
  int base = t*256;
  unsigned s = 0;
  for (int b=0;b<256;b++) s += hist[base+b];
  csum[t] = s; __syncthreads();
  if (t==0){ unsigned run=0; for (int u=255;u>=0;u--){ above[u]=run; run += csum[u]; } }
  __syncthreads();
  unsigned ab = above[t];
  if (ab < target && ab + csum[t] >= target){
    unsigned run = ab;
    for (int b = base+255; b >= base; b--){
      unsigned hb = hist[b];
      if (run + hb >= target){
        scal[2] = (scal[0] << 16) | (unsigned)b;
        scal[3] = target - run;
        scal[4] = hb;
        break;
      }
      run += hb;
    }
  }
}

__global__ void k_select(const unsigned* __restrict__ keys, const float* __restrict__ score,
    unsigned* __restrict__ scal, int* __restrict__ selidx, float* __restrict__ tvals){
  int i = blockIdx.x*blockDim.x + threadIdx.x;
  if (i >= NN) return;
  unsigned T = scal[2], needed = scal[3], cnteq = scal[4];
  unsigned k = keys[i];
  int s = 0;
  if (k > T) s = 1;
  else if (k == T){
    if (cnteq <= needed) s = 1;
    else {
      unsigned rank = 0;
      for (int j=0;j<i;j++) rank += (keys[j] == T) ? 1u : 0u;
      s = (rank < needed) ? 1 : 0;
    }
  }
  if (s){
    unsigned idx = atomicAdd(&scal[8], 1u);
    selidx[idx] = i;
    tvals[idx] = tanhf(score[i]);
  }
}

__global__ __launch_bounds__(256) void k_embed(const float* __restrict__ x2raw, const float* __restrict__ scale2,
    const float* __restrict__ shift2, const float* __restrict__ prelu2, const int* __restrict__ selidx,
    const float* __restrict__ tvals, float* __restrict__ embed){
  int c = threadIdx.x;
  float slope = prelu2[0];
  float scv = scale2[c], shv = shift2[c];
  float best = -INFINITY;
  for (int j = blockIdx.x; j < KT; j += gridDim.x){
    int r = selidx[j];
    float v = x2raw[(size_t)r*HH + c]*scv + shv;
    v = preluf(v, slope);
    best = fmaxf(best, v*tvals[j]);
  }
  atomicMaxF(&embed[c], best);
}

__global__ void k_initembed(float* __restrict__ embed){
  int i = threadIdx.x;
  if (i < 2*HH) embed[i] = -INFINITY;
}

// ---------------- head ----------------
__global__ __launch_bounds__(256) void k_head(const float* __restrict__ embed, const float* __restrict__ addf,
    const float* __restrict__ fc1W, const float* __restrict__ fc1b, const float* __restrict__ preluh,
    const float* __restrict__ fc2W, const float* __restrict__ fc2b, float* __restrict__ out){
  __shared__ float z[2*HH + 8];
  __shared__ float h1s[HH];
  __shared__ float red[4];
  int t = threadIdx.x;
  for (int i=t;i<2*HH;i+=256) z[i] = embed[i];
  if (t < 8) z[2*HH + t] = addf[t];
  __syncthreads();
  float acc = fc1b[t];
  for (int k=0;k<2*HH+8;k++) acc += z[k]*fc1W[(size_t)k*HH + t];
  float slope = preluh[0];
  h1s[t] = preluf(acc, slope);
  __syncthreads();
  float p = h1s[t]*fc2W[t];
  p = wredsum(p);
  if ((t & 63) == 0) red[t>>6] = p;
  __syncthreads();
  if (t == 0) out[0] = expf(red[0]+red[1]+red[2]+red[3] + fc2b[0]);
}

// ---------------- orchestration ----------------
extern "C" void kernel_launch(void* const* d_in, const int* in_sizes, int n_in,
                              void* d_out, int out_size, void* d_ws, size_t ws_size,
                              hipStream_t stream) {
  (void)in_sizes; (void)n_in; (void)out_size; (void)ws_size;
  char* ws = (char*)d_ws;
  size_t off = 0;
  auto alloc = [&](size_t bytes)->char*{
    char* p = ws + off;
    off = (off + bytes + 255) & ~(size_t)255;
    return p;
  };
  float* bufA   = (float*)alloc((size_t)NN*HH*4);   // h, later agg
  float* bufB   = (float*)alloc((size_t)NN*HH*4);   // gat out -> sage out (in-place) -> x2 source
  float* asrc   = (float*)alloc((size_t)NN*4);
  float* adst   = (float*)alloc((size_t)NN*4);
  int*   rowptr = (int*)  alloc((size_t)(NN+1)*4);
  int*   adj    = (int*)  alloc((size_t)NE*4);
  int*   cursor = (int*)  alloc((size_t)NN*4);
  int*   bsums  = (int*)  alloc(128*4);
  float* sums   = (float*)alloc((size_t)2*HH*4);
  float* sumsq  = sums + HH;
  float* scale1 = (float*)alloc((size_t)HH*4);
  float* shift1 = (float*)alloc((size_t)HH*4);
  float* scale2 = (float*)alloc((size_t)HH*4);
  float* shift2 = (float*)alloc((size_t)HH*4);
  float* y2     = (float*)alloc((size_t)NN*4);
  float* y2r    = (float*)alloc((size_t)NN*4);
  float* score  = (float*)alloc((size_t)NN*4);
  unsigned* keys= (unsigned*)alloc((size_t)NN*4);
  int*   selidx = (int*)  alloc((size_t)NN*4);
  float* tvals  = (float*)alloc((size_t)NN*4);
  unsigned* hist1 = (unsigned*)alloc(65536*4);
  unsigned* hist2 = (unsigned*)alloc(65536*4);
  unsigned* scal  = (unsigned*)alloc(64);
  float* embed  = (float*)alloc((size_t)2*HH*4);
  u16* WtT    = (u16*)alloc((size_t)16*16384*2);   // gemm2 weights, 512 KB
  u16* WtT1   = (u16*)alloc((size_t)2*16384*2);    // gemm1 weights, 64 KB

  const float* addf = (const float*)d_in[2];

  k_initembed<<<dim3(1), dim3(512), 0, stream>>>(embed);

  for (int br = 0; br < 2; br++){
    const float* x  = (const float*)d_in[br==0 ? 0 : 1];
    const int*   ei = (const int*)  d_in[br==0 ? 3 : 4];
    const int* esrc = ei;
    const int* edst = ei + NE;
    int p = br==0 ? 5 : 21;
    const float* gat_W    = (const float*)d_in[p+0];
    const float* gat_asrc = (const float*)d_in[p+1];
    const float* gat_adst = (const float*)d_in[p+2];
    const float* gat_b    = (const float*)d_in[p+3];
    const float* bn1_g    = (const float*)d_in[p+4];
    const float* bn1_b    = (const float*)d_in[p+5];
    const float* prelu1   = (const float*)d_in[p+6];
    const float* sage_Wl  = (const float*)d_in[p+7];
    const float* sage_bl  = (const float*)d_in[p+8];
    const float* sage_Wr  = (const float*)d_in[p+9];
    const float* bn2_g    = (const float*)d_in[p+10];
    const float* bn2_b    = (const float*)d_in[p+11];
    const float* prelu2   = (const float*)d_in[p+12];
    const float* pool_Wrel= (const float*)d_in[p+13];
    const float* pool_brel= (const float*)d_in[p+14];
    const float* pool_Wroot=(const float*)d_in[p+15];

    // CSR by dst
    hipMemsetAsync(cursor, 0, (size_t)NN*4, stream);
    k_count<<<dim3((NE+255)/256), dim3(256), 0, stream>>>(edst, cursor);
    k_scan1<<<dim3(98), dim3(1024), 0, stream>>>(cursor, rowptr, bsums);
    k_scan2<<<dim3(1), dim3(128), 0, stream>>>(bsums, 98);
    k_scan3<<<dim3(98), dim3(1024), 0, stream>>>(rowptr, bsums, cursor);
    k_scatter<<<dim3((NE+255)/256), dim3(256), 0, stream>>>(esrc, edst, cursor, adj);

    // W pre-splits (chunk-major fragment layout)
    k_splitW<<<dim3(512), dim3(256), 0, stream>>>(sage_Wr, sage_Wl, WtT);
    k_splitW1<<<dim3(64), dim3(256), 0, stream>>>(gat_W, WtT1);

    // GAT (MFMA gemm1 fuses the asrc/adst row-dots)
    k_gemm1<<<dim3((NN+63)/64), dim3(256), 0, stream>>>(x, WtT1, gat_asrc, gat_adst, bufA, asrc, adst);
    k_gat<<<dim3(25000), dim3(256), 0, stream>>>(bufA, asrc, adst, rowptr, adj, gat_b, bufB);

    // BN1
    hipMemsetAsync(sums, 0, (size_t)2*HH*4, stream);
    k_bnstats<<<dim3(512), dim3(256), 0, stream>>>(bufB, sums, sumsq);
    k_bnfin<<<dim3(1), dim3(256), 0, stream>>>(sums, sumsq, bn1_g, bn1_b, scale1, shift1);

    // SAGE (agg into bufA; MFMA GEMM in-place into bufB with fused BN2 stats)
    k_sageagg<<<dim3(25000), dim3(256), 0, stream>>>(bufB, scale1, shift1, prelu1, rowptr, adj, bufA);
    hipMemsetAsync(sums, 0, (size_t)2*HH*4, stream);
    k_gemm2<<<dim3((NN+63)/64), dim3(256), 0, stream>>>(bufB, bufA, WtT,
        scale1, shift1, prelu1, sage_bl, bufB, sums, sumsq);
    k_bnfin<<<dim3(1), dim3(256), 0, stream>>>(sums, sumsq, bn2_g, bn2_b, scale2, shift2);

    // SAGPool
    k_gemv2<<<dim3(25000), dim3(256), 0, stream>>>(bufB, scale2, shift2, prelu2, pool_Wrel, pool_Wroot, y2, y2r);
    k_score<<<dim3((NN+255)/256), dim3(256), 0, stream>>>(rowptr, adj, y2, y2r, pool_brel, score, keys);
    hipMemsetAsync(scal, 0, 64, stream);
    hipMemsetAsync(hist1, 0, 65536*4, stream);
    hipMemsetAsync(hist2, 0, 65536*4, stream);
    k_hist1<<<dim3((NN+255)/256), dim3(256), 0, stream>>>(keys, hist1);
    k_findbin1<<<dim3(1), dim3(256), 0, stream>>>(hist1, scal);
    k_hist2<<<dim3((NN+255)/256), dim3(256), 0, stream>>>(keys, scal, hist2);
    k_findbin2<<<dim3(1), dim3(256), 0, stream>>>(hist2, scal);
    k_select<<<dim3((NN+255)/256), dim3(256), 0, stream>>>(keys, score, scal, selidx, tvals);
    k_embed<<<dim3(256), dim3(256), 0, stream>>>(bufB, scale2, shift2, prelu2, selidx, tvals, embed + br*HH);
  }

  k_head<<<dim3(1), dim3(256), 0, stream>>>(embed, addf,
      (const float*)d_in[37], (const float*)d_in[38], (const float*)d_in[39],
      (const float*)d_in[40], (const float*)d_in[41], (float*)d_out);
}